// Round 9
// baseline (359.734 us; speedup 1.0000x reference)
//
#include <hip/hip_runtime.h>
#include <stdint.h>

typedef unsigned short u16;
typedef __attribute__((ext_vector_type(8))) short s16x8;   // 8 bf16 in 4 VGPRs
typedef __attribute__((ext_vector_type(4))) float f32x4;   // MFMA accumulator
typedef __attribute__((ext_vector_type(4))) unsigned uint4v;

#define NEXP 8
#define HD 1024
#define DFF 4096
#define BM 128
#define BN 128
#define BK 64     // 128B rows: full-line coalescing; XOR-swizzled LDS (T21 both-sides)
#define NPC 2048  // persistent convt blocks

__device__ __forceinline__ u16 f2bf(float f) {
  union { float f; unsigned u; } c; c.f = f;
  unsigned r = c.u + 0x7fffu + ((c.u >> 16) & 1u);   // RNE
  return (u16)(r >> 16);
}

__device__ __forceinline__ unsigned cvtpk(float a, float b) {
  unsigned r;
  asm("v_cvt_pk_bf16_f32 %0, %1, %2" : "=v"(r) : "v"(a), "v"(b));
  return r;   // lo = bf16(a), hi = bf16(b)
}

__device__ __forceinline__ void gload_lds16(const void* g, const void* l) {
  __builtin_amdgcn_global_load_lds(
      (const __attribute__((address_space(1))) unsigned int*)(uintptr_t)g,
      (__attribute__((address_space(3))) unsigned int*)(unsigned)(uintptr_t)l,
      16, 0, 0);
}

__global__ __launch_bounds__(64) void zero_k(int* counts) {
  if (threadIdx.x < NEXP) counts[threadIdx.x] = 0;
}

// LDS-free 64k x 64n transpose tile: W [K][N] f32 -> Wt [N][K] bf16.
// Thread owns one n-column: 16 lane-coalesced row loads (256B/instr), cvt_pk,
// 2x b128 k-contiguous stores (g-threads complete each 64B line -> L2 merge).
template <int K, int N>
__device__ __forceinline__ void convt_tile(const float* __restrict__ W,
                                           u16* __restrict__ Wt, int idx) {
  constexpr int TPE = (K / 64) * (N / 64);
  const int e = idx / TPE;
  const int ti = idx % TPE;
  const int k0 = (ti % (K / 64)) * 64;
  const int n0 = (ti / (K / 64)) * 64;
  const float* src = W + (size_t)e * K * N + (size_t)k0 * N + n0;
  const int n = threadIdx.x & 63;
  const int g = threadIdx.x >> 6;
  float v[16];
#pragma unroll
  for (int i = 0; i < 16; ++i)
    v[i] = src[(size_t)(g * 16 + i) * N + n];
  uint4v q0, q1;
#pragma unroll
  for (int j = 0; j < 4; ++j) {
    q0[j] = cvtpk(v[2 * j], v[2 * j + 1]);
    q1[j] = cvtpk(v[8 + 2 * j], v[9 + 2 * j]);
  }
  u16* d = Wt + (size_t)e * K * N + (size_t)(n0 + n) * K + k0 + g * 16;
  *(uint4v*)d = q0;
  *(uint4v*)(d + 8) = q1;
}

// prep1: persistent W1-transpose blocks (first) + router blocks (4 tok/block).
// Router also emits bf16 copy of x (Xbf) for the gather.
__global__ __launch_bounds__(256) void prep1_k(
    const float* __restrict__ x, const float* __restrict__ Wr,
    const float* __restrict__ br, int* __restrict__ counts,
    int* __restrict__ tok_exp, float* __restrict__ tok_gate,
    const float* __restrict__ W1, u16* __restrict__ W1t,
    u16* __restrict__ Xbf, int T) {
  const int bid = blockIdx.x;
  if (bid < NPC) {   // W1 [E][HD][DFF] -> W1t [E][DFF][HD], 8192 tiles
    constexpr int NTL = NEXP * (HD / 64) * (DFF / 64);
#pragma unroll
    for (int i = 0; i < NTL / NPC; ++i)
      convt_tile<HD, DFF>(W1, W1t, bid + i * NPC);
    return;
  }
  const int w = threadIdx.x >> 6, l = threadIdx.x & 63;
  const int t = (bid - NPC) * 4 + w;
  const float4* xr = (const float4*)(x + (size_t)t * HD);
  float acc[NEXP];
#pragma unroll
  for (int j = 0; j < NEXP; ++j) acc[j] = 0.f;
#pragma unroll
  for (int i = 0; i < 4; ++i) {
    float4 v = xr[l + i * 64];
    unsigned pa = cvtpk(v.x, v.y), pb = cvtpk(v.z, v.w);
    *(uint2*)&Xbf[(size_t)t * HD + (l + i * 64) * 4] = make_uint2(pa, pb);
    const int h = (l + i * 64) * 4;
    const float* w0 = Wr + (size_t)h * NEXP;
#pragma unroll
    for (int c = 0; c < 4; ++c) {
      float xv = (c == 0) ? v.x : (c == 1) ? v.y : (c == 2) ? v.z : v.w;
      const float4* wr4 = (const float4*)(w0 + c * NEXP);
      float4 a = wr4[0], b = wr4[1];
      acc[0] += xv * a.x; acc[1] += xv * a.y; acc[2] += xv * a.z; acc[3] += xv * a.w;
      acc[4] += xv * b.x; acc[5] += xv * b.y; acc[6] += xv * b.z; acc[7] += xv * b.w;
    }
  }
#pragma unroll
  for (int j = 0; j < NEXP; ++j)
#pragma unroll
    for (int off = 32; off > 0; off >>= 1) acc[j] += __shfl_xor(acc[j], off);
  if (l == 0) {
    float lg[NEXP];
    float best = acc[0] + br[0]; int bi = 0;
    lg[0] = best;
#pragma unroll
    for (int j = 1; j < NEXP; ++j) {
      lg[j] = acc[j] + br[j];
      if (lg[j] > best) { best = lg[j]; bi = j; }
    }
    float s = 0.f;
#pragma unroll
    for (int j = 0; j < NEXP; ++j) s += expf(lg[j] - best);
    tok_exp[t] = bi;
    tok_gate[t] = 1.0f / s;
    atomicAdd(&counts[bi], 1);
  }
}

__global__ __launch_bounds__(64) void scan_k(const int* __restrict__ counts,
    int* __restrict__ seg, int* __restrict__ cursor,
    int* __restrict__ ntile, int* __restrict__ tile_e, int* __restrict__ tile_m) {
  if (threadIdx.x == 0) {
    int s = 0, nt = 0;
#pragma unroll
    for (int e = 0; e < NEXP; ++e) {
      seg[e] = s; cursor[e] = s;
      int c = counts[e];
      for (int m = 0; m < c; m += BM) { tile_e[nt] = e; tile_m[nt] = m; ++nt; }
      s += c;
    }
    seg[NEXP] = s;
    ntile[0] = nt;
  }
}

// gather: permute bf16 rows (Xbf -> Xg), 4 tokens/block.
__global__ __launch_bounds__(256) void gather_k(const u16* __restrict__ Xbf,
    const int* __restrict__ tok_exp, const float* __restrict__ tok_gate,
    int* __restrict__ cursor, int* __restrict__ perm, float* __restrict__ gatep,
    u16* __restrict__ Xg) {
  const int w = threadIdx.x >> 6, l = threadIdx.x & 63;
  const int t = blockIdx.x * 4 + w;
  int pos = 0;
  if (l == 0) {
    int e = tok_exp[t];
    pos = atomicAdd(&cursor[e], 1);
    perm[pos] = t;
    gatep[pos] = tok_gate[t];
  }
  pos = __shfl(pos, 0);
  const s16x8* srcr = (const s16x8*)(Xbf + (size_t)t * HD);
  s16x8* dst = (s16x8*)(Xg + (size_t)pos * HD);
#pragma unroll
  for (int i = 0; i < HD / 8 / 64; ++i)
    dst[l + i * 64] = srcr[l + i * 64];
}

// m97-structure grouped GEMM body, BK=64, T21 XOR-swizzled LDS (chunk ^= row&7).
// A:[T][KD] bf16 (permuted rows), Bt:[E][ND][KD] bf16.
// EPI 0: H1out = bf16(relu(acc+bias)).   EPI 2: Pt[ks][row][n] = acc (f32 partial).
template <int KD, int ND, int EPI, int KSPLIT>
__device__ __forceinline__ void gemm_body(
    u16* __restrict__ As, u16* __restrict__ Bs,
    const u16* __restrict__ A, const u16* __restrict__ Bt,
    const float* __restrict__ bias, const int* __restrict__ seg,
    const int* __restrict__ ntile, const int* __restrict__ tile_e,
    const int* __restrict__ tile_m,
    u16* __restrict__ H1out, float* __restrict__ Pt,
    int bx, int by, int ks) {
  if (by >= ntile[0]) return;
  const int e  = tile_e[by];
  const int m0 = tile_m[by];
  const int s0 = seg[e];
  const int cnt = seg[e + 1] - s0;
  const int n0 = bx * BN;
  constexpr int NT = (KD / KSPLIT) / BK;
  const int kbase = ks * (KD / KSPLIT);

  const int t = threadIdx.x;
  const int l = t & 63, w = t >> 6;
  const int wr = w >> 1, wc = w & 1;

  const f32x4 fzero = {0.f, 0.f, 0.f, 0.f};
  f32x4 acc[4][4];
#pragma unroll
  for (int i = 0; i < 4; ++i)
#pragma unroll
    for (int j = 0; j < 4; ++j) acc[i][j] = fzero;

  const int sub = t & 7, r8 = t >> 3;
  const int koff = (sub ^ (r8 & 7)) * 8;
  int aoff[4], boff[4];
  const u16* bte = Bt + (size_t)e * ND * KD;
#pragma unroll
  for (int c = 0; c < 4; ++c) {
    int row = c * 32 + r8;
    int rg = m0 + row; if (rg >= cnt) rg = cnt - 1;
    aoff[c] = (s0 + rg) * KD + kbase + koff;
    boff[c] = (n0 + row) * KD + kbase + koff;
  }

  for (int tt = 0; tt < NT; ++tt) {
    __syncthreads();
    const int ko = tt * BK;
#pragma unroll
    for (int c = 0; c < 4; ++c)
      gload_lds16(A + (size_t)aoff[c] + ko, &As[(c * 256 + t) * 8]);
#pragma unroll
    for (int c = 0; c < 4; ++c)
      gload_lds16(bte + (size_t)boff[c] + ko, &Bs[(c * 256 + t) * 8]);
    __syncthreads();
#pragma unroll
    for (int s = 0; s < 2; ++s) {
      const int fo = ((s * 4 + (l >> 4)) ^ (l & 7)) * 8;
      s16x8 af[4], bfr[4];
#pragma unroll
      for (int mi = 0; mi < 4; ++mi)
        af[mi] = *(const s16x8*)&As[(wr * 64 + mi * 16 + (l & 15)) * BK + fo];
#pragma unroll
      for (int ni = 0; ni < 4; ++ni)
        bfr[ni] = *(const s16x8*)&Bs[(wc * 64 + ni * 16 + (l & 15)) * BK + fo];
#pragma unroll
      for (int mi = 0; mi < 4; ++mi)
#pragma unroll
        for (int ni = 0; ni < 4; ++ni)
          acc[mi][ni] = __builtin_amdgcn_mfma_f32_16x16x32_bf16(af[mi], bfr[ni], acc[mi][ni], 0, 0, 0);
    }
  }

  const int lr = (l >> 4) * 4;
  const int lc = l & 15;

  if constexpr (EPI == 0) {
    float bv2[4];
#pragma unroll
    for (int ni = 0; ni < 4; ++ni)
      bv2[ni] = bias[(size_t)e * ND + n0 + wc * 64 + ni * 16 + lc];
#pragma unroll
    for (int mi = 0; mi < 4; ++mi) {
#pragma unroll
      for (int r = 0; r < 4; ++r) {
        int row = m0 + wr * 64 + mi * 16 + lr + r;
        if (row < cnt) {
          u16* hrow = H1out + (size_t)(s0 + row) * ND + n0 + wc * 64;
#pragma unroll
          for (int ni = 0; ni < 4; ++ni) {
            float v = acc[mi][ni][r] + bv2[ni];
            v = v > 0.f ? v : 0.f;
            hrow[ni * 16 + lc] = f2bf(v);
          }
        }
      }
    }
  } else {
    const int totT = seg[NEXP];
#pragma unroll
    for (int mi = 0; mi < 4; ++mi) {
#pragma unroll
      for (int r = 0; r < 4; ++r) {
        int row = m0 + wr * 64 + mi * 16 + lr + r;
        if (row < cnt) {
          float* prow = Pt + ((size_t)ks * totT + s0 + row) * ND + n0 + wc * 64;
#pragma unroll
          for (int ni = 0; ni < 4; ++ni)
            prow[ni * 16 + lc] = acc[mi][ni][r];
        }
      }
    }
  }
}

// Fused: persistent W2-transpose blocks (first NPC) + GEMM1 blocks.
// W2t is only read by the NEXT launch (gemm2) -> completion guaranteed.
__global__ __launch_bounds__(256, 4) void gemm1_fused_k(
    const u16* __restrict__ Xg, const u16* __restrict__ W1t,
    const float* __restrict__ b1, const int* __restrict__ seg,
    const int* __restrict__ ntile, const int* __restrict__ tile_e,
    const int* __restrict__ tile_m, u16* __restrict__ H1,
    const float* __restrict__ W2, u16* __restrict__ W2t) {
  __shared__ __align__(16) u16 sh[2 * BM * BK];   // 32KB
  const int bid = blockIdx.x;
  if (bid < NPC) {   // W2 [E][DFF][HD] -> W2t [E][HD][DFF], 8192 tiles
    constexpr int NTL = NEXP * (DFF / 64) * (HD / 64);
#pragma unroll
    for (int i = 0; i < NTL / NPC; ++i)
      convt_tile<DFF, HD>(W2, W2t, bid + i * NPC);
  } else {
    const int g = bid - NPC;
    gemm_body<HD, DFF, 0, 1>(sh, sh + BM * BK, Xg, W1t, b1, seg, ntile, tile_e,
                             tile_m, H1, nullptr, g % (DFF / BN), g / (DFF / BN), 0);
  }
}

__global__ __launch_bounds__(256, 4) void gemm2_k(
    const u16* __restrict__ H1, const u16* __restrict__ W2t,
    const int* __restrict__ seg, const int* __restrict__ ntile,
    const int* __restrict__ tile_e, const int* __restrict__ tile_m,
    float* __restrict__ Pt) {
  __shared__ __align__(16) u16 sh[2 * BM * BK];
  gemm_body<DFF, HD, 2, 4>(sh, sh + BM * BK, H1, W2t, nullptr, seg, ntile, tile_e,
                           tile_m, nullptr, Pt, blockIdx.x, blockIdx.y, blockIdx.z);
}

// out[perm[pos]] = gate[pos] * (b2[e] + sum_ks Pt[ks][pos][:])
__global__ __launch_bounds__(256) void reduce_k(const float* __restrict__ Pt,
    const float* __restrict__ b2, const int* __restrict__ perm,
    const float* __restrict__ gatep, const int* __restrict__ tok_exp,
    float* __restrict__ out) {
  const int pos = blockIdx.x;
  const int totT = gridDim.x;
  const int tok = perm[pos];
  const float g = gatep[pos];
  const int e = tok_exp[tok];
  const int h = threadIdx.x * 4;
  float4 s = *(const float4*)(Pt + ((size_t)0 * totT + pos) * HD + h);
#pragma unroll
  for (int k = 1; k < 4; ++k) {
    float4 p = *(const float4*)(Pt + ((size_t)k * totT + pos) * HD + h);
    s.x += p.x; s.y += p.y; s.z += p.z; s.w += p.w;
  }
  float4 b = *(const float4*)(b2 + (size_t)e * HD + h);
  float4 o;
  o.x = (s.x + b.x) * g; o.y = (s.y + b.y) * g;
  o.z = (s.z + b.z) * g; o.w = (s.w + b.w) * g;
  *(float4*)(out + (size_t)tok * HD + h) = o;
}

extern "C" void kernel_launch(void* const* d_in, const int* in_sizes, int n_in,
                              void* d_out, int out_size, void* d_ws, size_t ws_size,
                              hipStream_t stream) {
  const float* x  = (const float*)d_in[0];
  const float* Wr = (const float*)d_in[1];
  const float* br = (const float*)d_in[2];
  const float* W1 = (const float*)d_in[3];
  const float* b1 = (const float*)d_in[4];
  const float* W2 = (const float*)d_in[5];
  const float* b2 = (const float*)d_in[6];
  float* out = (float*)d_out;

  const int T = in_sizes[0] / HD;   // 4096 tokens
  char* ws = (char*)d_ws;
  int*   counts   = (int*)(ws + 0);
  int*   cursor   = (int*)(ws + 64);
  int*   seg      = (int*)(ws + 128);
  int*   ntile    = (int*)(ws + 192);
  int*   tile_e   = (int*)(ws + 256);
  int*   tile_m   = (int*)(ws + 512);
  int*   tok_exp  = (int*)(ws + 1024);
  float* tok_gate = (float*)(ws + 1024 + 4 * (size_t)T);
  int*   perm     = (int*)(ws + 1024 + 8 * (size_t)T);
  float* gatep    = (float*)(ws + 1024 + 12 * (size_t)T);
  u16*   Xg       = (u16*)(ws + 1024 + 16 * (size_t)T);                       // T*HD bf16 (8MB)
  u16*   H1       = (u16*)(ws + 1024 + 16 * (size_t)T + 2 * (size_t)T * HD);  // T*DFF bf16 (32MB)
  size_t off2     = 1024 + 16 * (size_t)T + 2 * (size_t)T * HD + 2 * (size_t)T * DFF;
  u16*   W1t      = (u16*)(ws + off2);                                        // E*DFF*HD bf16 (64MB)
  u16*   W2t      = (u16*)(ws + off2 + 2 * (size_t)NEXP * HD * DFF);          // E*HD*DFF bf16 (64MB)
  float* Pt       = (float*)W1t;   // GEMM2 split-K partials (4*T*HD f32 = 64MB) reuse W1t
  u16*   Xbf      = H1;            // bf16 x (8MB) lives in H1's region until gather is done

  hipLaunchKernelGGL(zero_k, dim3(1), dim3(64), 0, stream, counts);
  hipLaunchKernelGGL(prep1_k, dim3(NPC + T / 4), dim3(256), 0, stream,
                     x, Wr, br, counts, tok_exp, tok_gate, W1, W1t, Xbf, T);
  hipLaunchKernelGGL(scan_k, dim3(1), dim3(64), 0, stream, counts, seg, cursor, ntile, tile_e, tile_m);
  hipLaunchKernelGGL(gather_k, dim3(T / 4), dim3(256), 0, stream,
                     Xbf, tok_exp, tok_gate, cursor, perm, gatep, Xg);
  const int maxtile = (T + BM - 1) / BM + NEXP - 1;   // 39 worst case
  const int ng1 = (DFF / BN) * maxtile;               // 1248 GEMM1 blocks
  hipLaunchKernelGGL(gemm1_fused_k, dim3(NPC + ng1), dim3(256), 0, stream,
                     Xg, W1t, b1, seg, ntile, tile_e, tile_m, H1, W2, W2t);
  hipLaunchKernelGGL(gemm2_k, dim3(HD / BN, maxtile, 4), dim3(256), 0, stream,
                     H1, W2t, seg, ntile, tile_e, tile_m, Pt);
  hipLaunchKernelGGL(reduce_k, dim3(T), dim3(256), 0, stream, Pt, b2, perm, gatep, tok_exp, out);
}

// Round 11
// 303.508 us; speedup vs baseline: 1.1853x; 1.1853x over previous
//
#include <hip/hip_runtime.h>
#include <stdint.h>

typedef unsigned short u16;
typedef __attribute__((ext_vector_type(8))) short s16x8;   // 8 bf16 in 4 VGPRs
typedef __attribute__((ext_vector_type(4))) float f32x4;   // MFMA accumulator
typedef __attribute__((ext_vector_type(4))) unsigned uint4v;

#define NEXP 8
#define HD 1024
#define DFF 4096
#define BM 128
#define BN 128
#define BK 64     // 128B rows: full-line coalescing; XOR-swizzled LDS (T21 both-sides)

#define CT_S 136  // convt LDS row stride (u16): 272B -> uniform banks for b128 ops

__device__ __forceinline__ u16 f2bf(float f) {
  union { float f; unsigned u; } c; c.f = f;
  unsigned r = c.u + 0x7fffu + ((c.u >> 16) & 1u);   // RNE
  return (u16)(r >> 16);
}

__device__ __forceinline__ unsigned cvtpk(float a, float b) {
  unsigned r;
  asm("v_cvt_pk_bf16_f32 %0, %1, %2" : "=v"(r) : "v"(a), "v"(b));
  return r;   // lo = bf16(a), hi = bf16(b)
}

__device__ __forceinline__ void gload_lds16(const void* g, const void* l) {
  __builtin_amdgcn_global_load_lds(
      (const __attribute__((address_space(1))) unsigned int*)(uintptr_t)g,
      (__attribute__((address_space(3))) unsigned int*)(unsigned)(uintptr_t)l,
      16, 0, 0);
}

__global__ __launch_bounds__(64) void zero_k(int* counts) {
  if (threadIdx.x < NEXP) counts[threadIdx.x] = 0;
}

// Pipelined 4-tile transpose+convert: W [K][N] f32 -> Wt [N][K] bf16.
// Tile = 128k x 64n (r8-proven LDS mapping, ~2x bank floor). Register
// double-buffer: tile i+1's 8x float4 loads issue before tile i's LDS/store
// phase -> HBM latency hides under barrier+ds+store work (T14).
template <int K, int N>
__device__ __forceinline__ void convt_quad(const float* __restrict__ W,
    u16* __restrict__ Wt, int b0, u16* __restrict__ T) {
  const int t = threadIdx.x;
  const int m = t & 15, g = t >> 4;
  const int kq = g * 8, nq = m * 4;
  constexpr int TPE = (K / 128) * (N / 64);   // 512 tiles/expert
  const float* sp[4];
  u16* dp[4];
#pragma unroll
  for (int i = 0; i < 4; ++i) {
    int idx = b0 + i;
    int e = idx / TPE, ti = idx % TPE;
    int k0 = (ti % (K / 128)) * 128, n0 = (ti / (K / 128)) * 64;
    sp[i] = W + (size_t)e * K * N + (size_t)(k0 + kq) * N + n0 + nq;
    dp[i] = Wt + (size_t)e * K * N + (size_t)(n0 + g) * K + k0 + m * 8;  // r adds 16*K
  }
  f32x4 va[8], vb[8];

#define LOADT(vv, i) do { \
    _Pragma("unroll") for (int q_ = 0; q_ < 8; ++q_) \
      vv[q_] = *(const f32x4*)(sp[i] + (size_t)q_ * N); \
  } while (0)
#define CONVT(vv) do { \
    _Pragma("unroll") for (int j_ = 0; j_ < 4; ++j_) { \
      uint4v q_; \
      q_[0] = cvtpk(vv[0][j_], vv[1][j_]); q_[1] = cvtpk(vv[2][j_], vv[3][j_]); \
      q_[2] = cvtpk(vv[4][j_], vv[5][j_]); q_[3] = cvtpk(vv[6][j_], vv[7][j_]); \
      *(uint4v*)&T[(nq + j_) * CT_S + kq] = q_; \
    } \
  } while (0)
#define STORT(i) do { \
    _Pragma("unroll") for (int r_ = 0; r_ < 4; ++r_) { \
      uint4v q_ = *(const uint4v*)&T[(r_ * 16 + g) * CT_S + m * 8]; \
      *(uint4v*)(dp[i] + (size_t)r_ * 16 * K) = q_; \
    } \
  } while (0)

  LOADT(va, 0);
  CONVT(va); LOADT(vb, 1);
  __syncthreads(); STORT(0); __syncthreads();
  CONVT(vb); LOADT(va, 2);
  __syncthreads(); STORT(1); __syncthreads();
  CONVT(va); LOADT(vb, 3);
  __syncthreads(); STORT(2); __syncthreads();
  CONVT(vb);
  __syncthreads(); STORT(3);

#undef LOADT
#undef CONVT
#undef STORT
}

// prep1: persistent W1-transpose blocks (first NCB) + router blocks (4 tok/block).
// Router also emits bf16 copy of x (Xbf) for the gather.
__global__ __launch_bounds__(256) void prep1_k(
    const float* __restrict__ x, const float* __restrict__ Wr,
    const float* __restrict__ br, int* __restrict__ counts,
    int* __restrict__ tok_exp, float* __restrict__ tok_gate,
    const float* __restrict__ W1, u16* __restrict__ W1t,
    u16* __restrict__ Xbf, int T) {
  __shared__ __align__(16) u16 Tt[64 * CT_S];
  const int bid = blockIdx.x;
  constexpr int NCB = NEXP * (HD / 128) * (DFF / 64) / 4;   // 1024 blocks, 4 tiles each
  if (bid < NCB) {
    convt_quad<HD, DFF>(W1, W1t, bid * 4, Tt);   // W1 [E][HD][DFF] -> [E][DFF][HD]
    return;
  }
  const int w = threadIdx.x >> 6, l = threadIdx.x & 63;
  const int t = (bid - NCB) * 4 + w;
  const float4* xr = (const float4*)(x + (size_t)t * HD);
  float acc[NEXP];
#pragma unroll
  for (int j = 0; j < NEXP; ++j) acc[j] = 0.f;
#pragma unroll
  for (int i = 0; i < 4; ++i) {
    float4 v = xr[l + i * 64];
    unsigned pa = cvtpk(v.x, v.y), pb = cvtpk(v.z, v.w);
    *(uint2*)&Xbf[(size_t)t * HD + (l + i * 64) * 4] = make_uint2(pa, pb);
    const int h = (l + i * 64) * 4;
    const float* w0 = Wr + (size_t)h * NEXP;
#pragma unroll
    for (int c = 0; c < 4; ++c) {
      float xv = (c == 0) ? v.x : (c == 1) ? v.y : (c == 2) ? v.z : v.w;
      const float4* wr4 = (const float4*)(w0 + c * NEXP);
      float4 a = wr4[0], b = wr4[1];
      acc[0] += xv * a.x; acc[1] += xv * a.y; acc[2] += xv * a.z; acc[3] += xv * a.w;
      acc[4] += xv * b.x; acc[5] += xv * b.y; acc[6] += xv * b.z; acc[7] += xv * b.w;
    }
  }
#pragma unroll
  for (int j = 0; j < NEXP; ++j)
#pragma unroll
    for (int off = 32; off > 0; off >>= 1) acc[j] += __shfl_xor(acc[j], off);
  if (l == 0) {
    float lg[NEXP];
    float best = acc[0] + br[0]; int bi = 0;
    lg[0] = best;
#pragma unroll
    for (int j = 1; j < NEXP; ++j) {
      lg[j] = acc[j] + br[j];
      if (lg[j] > best) { best = lg[j]; bi = j; }
    }
    float s = 0.f;
#pragma unroll
    for (int j = 0; j < NEXP; ++j) s += expf(lg[j] - best);
    tok_exp[t] = bi;
    tok_gate[t] = 1.0f / s;
    atomicAdd(&counts[bi], 1);
  }
}

__global__ __launch_bounds__(64) void scan_k(const int* __restrict__ counts,
    int* __restrict__ seg, int* __restrict__ cursor,
    int* __restrict__ ntile, int* __restrict__ tile_e, int* __restrict__ tile_m) {
  if (threadIdx.x == 0) {
    int s = 0, nt = 0;
#pragma unroll
    for (int e = 0; e < NEXP; ++e) {
      seg[e] = s; cursor[e] = s;
      int c = counts[e];
      for (int m = 0; m < c; m += BM) { tile_e[nt] = e; tile_m[nt] = m; ++nt; }
      s += c;
    }
    seg[NEXP] = s;
    ntile[0] = nt;
  }
}

// gather: permute bf16 rows (Xbf -> Xg), 4 tokens/block.
__global__ __launch_bounds__(256) void gather_k(const u16* __restrict__ Xbf,
    const int* __restrict__ tok_exp, const float* __restrict__ tok_gate,
    int* __restrict__ cursor, int* __restrict__ perm, float* __restrict__ gatep,
    u16* __restrict__ Xg) {
  const int w = threadIdx.x >> 6, l = threadIdx.x & 63;
  const int t = blockIdx.x * 4 + w;
  int pos = 0;
  if (l == 0) {
    int e = tok_exp[t];
    pos = atomicAdd(&cursor[e], 1);
    perm[pos] = t;
    gatep[pos] = tok_gate[t];
  }
  pos = __shfl(pos, 0);
  const s16x8* srcr = (const s16x8*)(Xbf + (size_t)t * HD);
  s16x8* dst = (s16x8*)(Xg + (size_t)pos * HD);
#pragma unroll
  for (int i = 0; i < HD / 8 / 64; ++i)
    dst[l + i * 64] = srcr[l + i * 64];
}

// m97-structure grouped GEMM body, BK=64, T21 XOR-swizzled LDS (chunk ^= row&7).
// A:[T][KD] bf16 (permuted rows), Bt:[E][ND][KD] bf16.  [r8-proven, unchanged]
// EPI 0: H1out = bf16(relu(acc+bias)).   EPI 2: Pt[ks][row][n] = acc (f32 partial).
template <int KD, int ND, int EPI, int KSPLIT>
__device__ __forceinline__ void gemm_body(
    u16* __restrict__ As, u16* __restrict__ Bs,
    const u16* __restrict__ A, const u16* __restrict__ Bt,
    const float* __restrict__ bias, const int* __restrict__ seg,
    const int* __restrict__ ntile, const int* __restrict__ tile_e,
    const int* __restrict__ tile_m,
    u16* __restrict__ H1out, float* __restrict__ Pt,
    int bx, int by, int ks) {
  if (by >= ntile[0]) return;
  const int e  = tile_e[by];
  const int m0 = tile_m[by];
  const int s0 = seg[e];
  const int cnt = seg[e + 1] - s0;
  const int n0 = bx * BN;
  constexpr int NT = (KD / KSPLIT) / BK;
  const int kbase = ks * (KD / KSPLIT);

  const int t = threadIdx.x;
  const int l = t & 63, w = t >> 6;
  const int wr = w >> 1, wc = w & 1;

  const f32x4 fzero = {0.f, 0.f, 0.f, 0.f};
  f32x4 acc[4][4];
#pragma unroll
  for (int i = 0; i < 4; ++i)
#pragma unroll
    for (int j = 0; j < 4; ++j) acc[i][j] = fzero;

  const int sub = t & 7, r8 = t >> 3;
  const int koff = (sub ^ (r8 & 7)) * 8;
  int aoff[4], boff[4];
  const u16* bte = Bt + (size_t)e * ND * KD;
#pragma unroll
  for (int c = 0; c < 4; ++c) {
    int row = c * 32 + r8;
    int rg = m0 + row; if (rg >= cnt) rg = cnt - 1;
    aoff[c] = (s0 + rg) * KD + kbase + koff;
    boff[c] = (n0 + row) * KD + kbase + koff;
  }

  for (int tt = 0; tt < NT; ++tt) {
    __syncthreads();
    const int ko = tt * BK;
#pragma unroll
    for (int c = 0; c < 4; ++c)
      gload_lds16(A + (size_t)aoff[c] + ko, &As[(c * 256 + t) * 8]);
#pragma unroll
    for (int c = 0; c < 4; ++c)
      gload_lds16(bte + (size_t)boff[c] + ko, &Bs[(c * 256 + t) * 8]);
    __syncthreads();
#pragma unroll
    for (int s = 0; s < 2; ++s) {
      const int fo = ((s * 4 + (l >> 4)) ^ (l & 7)) * 8;
      s16x8 af[4], bfr[4];
#pragma unroll
      for (int mi = 0; mi < 4; ++mi)
        af[mi] = *(const s16x8*)&As[(wr * 64 + mi * 16 + (l & 15)) * BK + fo];
#pragma unroll
      for (int ni = 0; ni < 4; ++ni)
        bfr[ni] = *(const s16x8*)&Bs[(wc * 64 + ni * 16 + (l & 15)) * BK + fo];
#pragma unroll
      for (int mi = 0; mi < 4; ++mi)
#pragma unroll
        for (int ni = 0; ni < 4; ++ni)
          acc[mi][ni] = __builtin_amdgcn_mfma_f32_16x16x32_bf16(af[mi], bfr[ni], acc[mi][ni], 0, 0, 0);
    }
  }

  const int lr = (l >> 4) * 4;
  const int lc = l & 15;

  if constexpr (EPI == 0) {
    float bv2[4];
#pragma unroll
    for (int ni = 0; ni < 4; ++ni)
      bv2[ni] = bias[(size_t)e * ND + n0 + wc * 64 + ni * 16 + lc];
#pragma unroll
    for (int mi = 0; mi < 4; ++mi) {
#pragma unroll
      for (int r = 0; r < 4; ++r) {
        int row = m0 + wr * 64 + mi * 16 + lr + r;
        if (row < cnt) {
          u16* hrow = H1out + (size_t)(s0 + row) * ND + n0 + wc * 64;
#pragma unroll
          for (int ni = 0; ni < 4; ++ni) {
            float v = acc[mi][ni][r] + bv2[ni];
            v = v > 0.f ? v : 0.f;
            hrow[ni * 16 + lc] = f2bf(v);
          }
        }
      }
    }
  } else {
    const int totT = seg[NEXP];
#pragma unroll
    for (int mi = 0; mi < 4; ++mi) {
#pragma unroll
      for (int r = 0; r < 4; ++r) {
        int row = m0 + wr * 64 + mi * 16 + lr + r;
        if (row < cnt) {
          float* prow = Pt + ((size_t)ks * totT + s0 + row) * ND + n0 + wc * 64;
#pragma unroll
          for (int ni = 0; ni < 4; ++ni)
            prow[ni * 16 + lc] = acc[mi][ni][r];
        }
      }
    }
  }
}

// Fused: GEMM1 blocks first, then persistent W2-transpose blocks.
// W2t is only read by the NEXT launch (gemm2) -> completion guaranteed.
__global__ __launch_bounds__(256, 4) void gemm1_fused_k(
    const u16* __restrict__ Xg, const u16* __restrict__ W1t,
    const float* __restrict__ b1, const int* __restrict__ seg,
    const int* __restrict__ ntile, const int* __restrict__ tile_e,
    const int* __restrict__ tile_m, u16* __restrict__ H1,
    const float* __restrict__ W2, u16* __restrict__ W2t, int ng1) {
  __shared__ __align__(16) u16 sh[2 * BM * BK];   // 32KB; convt uses 17408B
  const int bid = blockIdx.x;
  if (bid < ng1) {
    gemm_body<HD, DFF, 0, 1>(sh, sh + BM * BK, Xg, W1t, b1, seg, ntile, tile_e,
                             tile_m, H1, nullptr, bid % (DFF / BN), bid / (DFF / BN), 0);
  } else {
    convt_quad<DFF, HD>(W2, W2t, (bid - ng1) * 4, sh);   // W2 [E][DFF][HD] -> [E][HD][DFF]
  }
}

__global__ __launch_bounds__(256, 4) void gemm2_k(
    const u16* __restrict__ H1, const u16* __restrict__ W2t,
    const int* __restrict__ seg, const int* __restrict__ ntile,
    const int* __restrict__ tile_e, const int* __restrict__ tile_m,
    float* __restrict__ Pt) {
  __shared__ __align__(16) u16 sh[2 * BM * BK];
  gemm_body<DFF, HD, 2, 4>(sh, sh + BM * BK, H1, W2t, nullptr, seg, ntile, tile_e,
                           tile_m, nullptr, Pt, blockIdx.x, blockIdx.y, blockIdx.z);
}

// out[perm[pos]] = gate[pos] * (b2[e] + sum_ks Pt[ks][pos][:])
__global__ __launch_bounds__(256) void reduce_k(const float* __restrict__ Pt,
    const float* __restrict__ b2, const int* __restrict__ perm,
    const float* __restrict__ gatep, const int* __restrict__ tok_exp,
    float* __restrict__ out) {
  const int pos = blockIdx.x;
  const int totT = gridDim.x;
  const int tok = perm[pos];
  const float g = gatep[pos];
  const int e = tok_exp[tok];
  const int h = threadIdx.x * 4;
  float4 s = *(const float4*)(Pt + ((size_t)0 * totT + pos) * HD + h);
#pragma unroll
  for (int k = 1; k < 4; ++k) {
    float4 p = *(const float4*)(Pt + ((size_t)k * totT + pos) * HD + h);
    s.x += p.x; s.y += p.y; s.z += p.z; s.w += p.w;
  }
  float4 b = *(const float4*)(b2 + (size_t)e * HD + h);
  float4 o;
  o.x = (s.x + b.x) * g; o.y = (s.y + b.y) * g;
  o.z = (s.z + b.z) * g; o.w = (s.w + b.w) * g;
  *(float4*)(out + (size_t)tok * HD + h) = o;
}

extern "C" void kernel_launch(void* const* d_in, const int* in_sizes, int n_in,
                              void* d_out, int out_size, void* d_ws, size_t ws_size,
                              hipStream_t stream) {
  const float* x  = (const float*)d_in[0];
  const float* Wr = (const float*)d_in[1];
  const float* br = (const float*)d_in[2];
  const float* W1 = (const float*)d_in[3];
  const float* b1 = (const float*)d_in[4];
  const float* W2 = (const float*)d_in[5];
  const float* b2 = (const float*)d_in[6];
  float* out = (float*)d_out;

  const int T = in_sizes[0] / HD;   // 4096 tokens
  char* ws = (char*)d_ws;
  int*   counts   = (int*)(ws + 0);
  int*   cursor   = (int*)(ws + 64);
  int*   seg      = (int*)(ws + 128);
  int*   ntile    = (int*)(ws + 192);
  int*   tile_e   = (int*)(ws + 256);
  int*   tile_m   = (int*)(ws + 512);
  int*   tok_exp  = (int*)(ws + 1024);
  float* tok_gate = (float*)(ws + 1024 + 4 * (size_t)T);
  int*   perm     = (int*)(ws + 1024 + 8 * (size_t)T);
  float* gatep    = (float*)(ws + 1024 + 12 * (size_t)T);
  u16*   Xg       = (u16*)(ws + 1024 + 16 * (size_t)T);                       // T*HD bf16 (8MB)
  u16*   H1       = (u16*)(ws + 1024 + 16 * (size_t)T + 2 * (size_t)T * HD);  // T*DFF bf16 (32MB)
  size_t off2     = 1024 + 16 * (size_t)T + 2 * (size_t)T * HD + 2 * (size_t)T * DFF;
  u16*   W1t      = (u16*)(ws + off2);                                        // E*DFF*HD bf16 (64MB)
  u16*   W2t      = (u16*)(ws + off2 + 2 * (size_t)NEXP * HD * DFF);          // E*HD*DFF bf16 (64MB)
  float* Pt       = (float*)W1t;   // GEMM2 split-K partials (4*T*HD f32 = 64MB) reuse W1t
  u16*   Xbf      = H1;            // bf16 x (8MB) lives in H1's region until gather is done

  hipLaunchKernelGGL(zero_k, dim3(1), dim3(64), 0, stream, counts);
  const int NCB = NEXP * (HD / 128) * (DFF / 64) / 4;   // 1024 convt blocks (4 tiles each)
  hipLaunchKernelGGL(prep1_k, dim3(NCB + T / 4), dim3(256), 0, stream,
                     x, Wr, br, counts, tok_exp, tok_gate, W1, W1t, Xbf, T);
  hipLaunchKernelGGL(scan_k, dim3(1), dim3(64), 0, stream, counts, seg, cursor, ntile, tile_e, tile_m);
  hipLaunchKernelGGL(gather_k, dim3(T / 4), dim3(256), 0, stream,
                     Xbf, tok_exp, tok_gate, cursor, perm, gatep, Xg);
  const int maxtile = (T + BM - 1) / BM + NEXP - 1;   // 39 worst case
  const int ng1 = (DFF / BN) * maxtile;               // 1248 GEMM1 blocks
  hipLaunchKernelGGL(gemm1_fused_k, dim3(ng1 + NCB), dim3(256), 0, stream,
                     Xg, W1t, b1, seg, ntile, tile_e, tile_m, H1, W2, W2t, ng1);
  hipLaunchKernelGGL(gemm2_k, dim3(HD / BN, maxtile, 4), dim3(256), 0, stream,
                     H1, W2t, seg, ntile, tile_e, tile_m, Pt);
  hipLaunchKernelGGL(reduce_k, dim3(T), dim3(256), 0, stream, Pt, b2, perm, gatep, tok_exp, out);
}

// Round 12
// 301.709 us; speedup vs baseline: 1.1923x; 1.0060x over previous
//
#include <hip/hip_runtime.h>
#include <stdint.h>

typedef unsigned short u16;
typedef __attribute__((ext_vector_type(8))) short s16x8;   // 8 bf16 in 4 VGPRs
typedef __attribute__((ext_vector_type(4))) float f32x4;   // MFMA accumulator
typedef __attribute__((ext_vector_type(4))) unsigned uint4v;

#define NEXP 8
#define HD 1024
#define DFF 4096
#define BM 128
#define BN 128
#define BK 64     // 128B rows: full-line coalescing; XOR-swizzled LDS (T21 both-sides)

#define CT_S 136  // convt LDS row stride (u16): 272B -> uniform banks for b128 ops

__device__ __forceinline__ u16 f2bf(float f) {
  union { float f; unsigned u; } c; c.f = f;
  unsigned r = c.u + 0x7fffu + ((c.u >> 16) & 1u);   // RNE
  return (u16)(r >> 16);
}

__device__ __forceinline__ unsigned cvtpk(float a, float b) {
  unsigned r;
  asm("v_cvt_pk_bf16_f32 %0, %1, %2" : "=v"(r) : "v"(a), "v"(b));
  return r;   // lo = bf16(a), hi = bf16(b)
}

__device__ __forceinline__ void gload_lds16(const void* g, const void* l) {
  __builtin_amdgcn_global_load_lds(
      (const __attribute__((address_space(1))) unsigned int*)(uintptr_t)g,
      (__attribute__((address_space(3))) unsigned int*)(unsigned)(uintptr_t)l,
      16, 0, 0);
}

// LDS-only barrier: drains ds ops, leaves global loads IN FLIGHT (unlike
// __syncthreads(), which emits s_waitcnt vmcnt(0) and kills load pipelining).
__device__ __forceinline__ void lds_barrier() {
  asm volatile("s_waitcnt lgkmcnt(0)" ::: "memory");
  __builtin_amdgcn_s_barrier();
  __builtin_amdgcn_sched_barrier(0);
}

__global__ __launch_bounds__(64) void zero_k(int* counts) {
  if (threadIdx.x < NEXP) counts[threadIdx.x] = 0;
}

// Pipelined 4-tile transpose+convert: W [K][N] f32 -> Wt [N][K] bf16.
// Tile = 128k x 64n (r8-proven LDS mapping). Depth-2 register prefetch with
// LDS-only barriers: global loads for tiles i+1, i+2 stay in flight across
// the store phase of tile i (compiler inserts counted vmcnt on va/vb use).
template <int K, int N>
__device__ __forceinline__ void convt_quad(const float* __restrict__ W,
    u16* __restrict__ Wt, int b0, u16* __restrict__ T) {
  const int t = threadIdx.x;
  const int m = t & 15, g = t >> 4;
  const int kq = g * 8, nq = m * 4;
  constexpr int TPE = (K / 128) * (N / 64);   // 512 tiles/expert
  const float* sp[4];
  u16* dp[4];
#pragma unroll
  for (int i = 0; i < 4; ++i) {
    int idx = b0 + i;
    int e = idx / TPE, ti = idx % TPE;
    int k0 = (ti % (K / 128)) * 128, n0 = (ti / (K / 128)) * 64;
    sp[i] = W + (size_t)e * K * N + (size_t)(k0 + kq) * N + n0 + nq;
    dp[i] = Wt + (size_t)e * K * N + (size_t)(n0 + g) * K + k0 + m * 8;  // r adds 16*K
  }
  f32x4 va[8], vb[8];

#define LOADT(vv, i) do { \
    _Pragma("unroll") for (int q_ = 0; q_ < 8; ++q_) \
      vv[q_] = *(const f32x4*)(sp[i] + (size_t)q_ * N); \
  } while (0)
#define CONVT(vv) do { \
    _Pragma("unroll") for (int j_ = 0; j_ < 4; ++j_) { \
      uint4v q_; \
      q_[0] = cvtpk(vv[0][j_], vv[1][j_]); q_[1] = cvtpk(vv[2][j_], vv[3][j_]); \
      q_[2] = cvtpk(vv[4][j_], vv[5][j_]); q_[3] = cvtpk(vv[6][j_], vv[7][j_]); \
      *(uint4v*)&T[(nq + j_) * CT_S + kq] = q_; \
    } \
  } while (0)
#define STORT(i) do { \
    _Pragma("unroll") for (int r_ = 0; r_ < 4; ++r_) { \
      uint4v q_ = *(const uint4v*)&T[(r_ * 16 + g) * CT_S + m * 8]; \
      *(uint4v*)(dp[i] + (size_t)r_ * 16 * K) = q_; \
    } \
  } while (0)

  LOADT(va, 0); LOADT(vb, 1);          // both tiles in flight
  CONVT(va); LOADT(va, 2);             // va consumed -> refill with tile 2
  lds_barrier(); STORT(0); lds_barrier();
  CONVT(vb); LOADT(vb, 3);             // vb consumed -> refill with tile 3
  lds_barrier(); STORT(1); lds_barrier();
  CONVT(va);
  lds_barrier(); STORT(2); lds_barrier();
  CONVT(vb);
  lds_barrier(); STORT(3);

#undef LOADT
#undef CONVT
#undef STORT
}

// prep1: persistent W1-transpose blocks (first NCB) + router blocks (4 tok/block).
// Router also emits bf16 copy of x (Xbf) for the gather.
__global__ __launch_bounds__(256) void prep1_k(
    const float* __restrict__ x, const float* __restrict__ Wr,
    const float* __restrict__ br, int* __restrict__ counts,
    int* __restrict__ tok_exp, float* __restrict__ tok_gate,
    const float* __restrict__ W1, u16* __restrict__ W1t,
    u16* __restrict__ Xbf, int T) {
  __shared__ __align__(16) u16 Tt[64 * CT_S];
  const int bid = blockIdx.x;
  constexpr int NCB = NEXP * (HD / 128) * (DFF / 64) / 4;   // 1024 blocks, 4 tiles each
  if (bid < NCB) {
    convt_quad<HD, DFF>(W1, W1t, bid * 4, Tt);   // W1 [E][HD][DFF] -> [E][DFF][HD]
    return;
  }
  const int w = threadIdx.x >> 6, l = threadIdx.x & 63;
  const int t = (bid - NCB) * 4 + w;
  const float4* xr = (const float4*)(x + (size_t)t * HD);
  float acc[NEXP];
#pragma unroll
  for (int j = 0; j < NEXP; ++j) acc[j] = 0.f;
#pragma unroll
  for (int i = 0; i < 4; ++i) {
    float4 v = xr[l + i * 64];
    unsigned pa = cvtpk(v.x, v.y), pb = cvtpk(v.z, v.w);
    *(uint2*)&Xbf[(size_t)t * HD + (l + i * 64) * 4] = make_uint2(pa, pb);
    const int h = (l + i * 64) * 4;
    const float* w0 = Wr + (size_t)h * NEXP;
#pragma unroll
    for (int c = 0; c < 4; ++c) {
      float xv = (c == 0) ? v.x : (c == 1) ? v.y : (c == 2) ? v.z : v.w;
      const float4* wr4 = (const float4*)(w0 + c * NEXP);
      float4 a = wr4[0], b = wr4[1];
      acc[0] += xv * a.x; acc[1] += xv * a.y; acc[2] += xv * a.z; acc[3] += xv * a.w;
      acc[4] += xv * b.x; acc[5] += xv * b.y; acc[6] += xv * b.z; acc[7] += xv * b.w;
    }
  }
#pragma unroll
  for (int j = 0; j < NEXP; ++j)
#pragma unroll
    for (int off = 32; off > 0; off >>= 1) acc[j] += __shfl_xor(acc[j], off);
  if (l == 0) {
    float lg[NEXP];
    float best = acc[0] + br[0]; int bi = 0;
    lg[0] = best;
#pragma unroll
    for (int j = 1; j < NEXP; ++j) {
      lg[j] = acc[j] + br[j];
      if (lg[j] > best) { best = lg[j]; bi = j; }
    }
    float s = 0.f;
#pragma unroll
    for (int j = 0; j < NEXP; ++j) s += expf(lg[j] - best);
    tok_exp[t] = bi;
    tok_gate[t] = 1.0f / s;
    atomicAdd(&counts[bi], 1);
  }
}

__global__ __launch_bounds__(64) void scan_k(const int* __restrict__ counts,
    int* __restrict__ seg, int* __restrict__ cursor,
    int* __restrict__ ntile, int* __restrict__ tile_e, int* __restrict__ tile_m) {
  if (threadIdx.x == 0) {
    int s = 0, nt = 0;
#pragma unroll
    for (int e = 0; e < NEXP; ++e) {
      seg[e] = s; cursor[e] = s;
      int c = counts[e];
      for (int m = 0; m < c; m += BM) { tile_e[nt] = e; tile_m[nt] = m; ++nt; }
      s += c;
    }
    seg[NEXP] = s;
    ntile[0] = nt;
  }
}

// gather: permute bf16 rows (Xbf -> Xg), 4 tokens/block.
__global__ __launch_bounds__(256) void gather_k(const u16* __restrict__ Xbf,
    const int* __restrict__ tok_exp, const float* __restrict__ tok_gate,
    int* __restrict__ cursor, int* __restrict__ perm, float* __restrict__ gatep,
    u16* __restrict__ Xg) {
  const int w = threadIdx.x >> 6, l = threadIdx.x & 63;
  const int t = blockIdx.x * 4 + w;
  int pos = 0;
  if (l == 0) {
    int e = tok_exp[t];
    pos = atomicAdd(&cursor[e], 1);
    perm[pos] = t;
    gatep[pos] = tok_gate[t];
  }
  pos = __shfl(pos, 0);
  const s16x8* srcr = (const s16x8*)(Xbf + (size_t)t * HD);
  s16x8* dst = (s16x8*)(Xg + (size_t)pos * HD);
#pragma unroll
  for (int i = 0; i < HD / 8 / 64; ++i)
    dst[l + i * 64] = srcr[l + i * 64];
}

// m97-structure grouped GEMM body, BK=64, T21 XOR-swizzled LDS (chunk ^= row&7).
// A:[T][KD] bf16 (permuted rows), Bt:[E][ND][KD] bf16.  [r8-proven, unchanged]
// EPI 0: H1out = bf16(relu(acc+bias)).   EPI 2: Pt[ks][row][n] = acc (f32 partial).
template <int KD, int ND, int EPI, int KSPLIT>
__device__ __forceinline__ void gemm_body(
    u16* __restrict__ As, u16* __restrict__ Bs,
    const u16* __restrict__ A, const u16* __restrict__ Bt,
    const float* __restrict__ bias, const int* __restrict__ seg,
    const int* __restrict__ ntile, const int* __restrict__ tile_e,
    const int* __restrict__ tile_m,
    u16* __restrict__ H1out, float* __restrict__ Pt,
    int bx, int by, int ks) {
  if (by >= ntile[0]) return;
  const int e  = tile_e[by];
  const int m0 = tile_m[by];
  const int s0 = seg[e];
  const int cnt = seg[e + 1] - s0;
  const int n0 = bx * BN;
  constexpr int NT = (KD / KSPLIT) / BK;
  const int kbase = ks * (KD / KSPLIT);

  const int t = threadIdx.x;
  const int l = t & 63, w = t >> 6;
  const int wr = w >> 1, wc = w & 1;

  const f32x4 fzero = {0.f, 0.f, 0.f, 0.f};
  f32x4 acc[4][4];
#pragma unroll
  for (int i = 0; i < 4; ++i)
#pragma unroll
    for (int j = 0; j < 4; ++j) acc[i][j] = fzero;

  const int sub = t & 7, r8 = t >> 3;
  const int koff = (sub ^ (r8 & 7)) * 8;
  int aoff[4], boff[4];
  const u16* bte = Bt + (size_t)e * ND * KD;
#pragma unroll
  for (int c = 0; c < 4; ++c) {
    int row = c * 32 + r8;
    int rg = m0 + row; if (rg >= cnt) rg = cnt - 1;
    aoff[c] = (s0 + rg) * KD + kbase + koff;
    boff[c] = (n0 + row) * KD + kbase + koff;
  }

  for (int tt = 0; tt < NT; ++tt) {
    __syncthreads();
    const int ko = tt * BK;
#pragma unroll
    for (int c = 0; c < 4; ++c)
      gload_lds16(A + (size_t)aoff[c] + ko, &As[(c * 256 + t) * 8]);
#pragma unroll
    for (int c = 0; c < 4; ++c)
      gload_lds16(bte + (size_t)boff[c] + ko, &Bs[(c * 256 + t) * 8]);
    __syncthreads();
#pragma unroll
    for (int s = 0; s < 2; ++s) {
      const int fo = ((s * 4 + (l >> 4)) ^ (l & 7)) * 8;
      s16x8 af[4], bfr[4];
#pragma unroll
      for (int mi = 0; mi < 4; ++mi)
        af[mi] = *(const s16x8*)&As[(wr * 64 + mi * 16 + (l & 15)) * BK + fo];
#pragma unroll
      for (int ni = 0; ni < 4; ++ni)
        bfr[ni] = *(const s16x8*)&Bs[(wc * 64 + ni * 16 + (l & 15)) * BK + fo];
#pragma unroll
      for (int mi = 0; mi < 4; ++mi)
#pragma unroll
        for (int ni = 0; ni < 4; ++ni)
          acc[mi][ni] = __builtin_amdgcn_mfma_f32_16x16x32_bf16(af[mi], bfr[ni], acc[mi][ni], 0, 0, 0);
    }
  }

  const int lr = (l >> 4) * 4;
  const int lc = l & 15;

  if constexpr (EPI == 0) {
    float bv2[4];
#pragma unroll
    for (int ni = 0; ni < 4; ++ni)
      bv2[ni] = bias[(size_t)e * ND + n0 + wc * 64 + ni * 16 + lc];
#pragma unroll
    for (int mi = 0; mi < 4; ++mi) {
#pragma unroll
      for (int r = 0; r < 4; ++r) {
        int row = m0 + wr * 64 + mi * 16 + lr + r;
        if (row < cnt) {
          u16* hrow = H1out + (size_t)(s0 + row) * ND + n0 + wc * 64;
#pragma unroll
          for (int ni = 0; ni < 4; ++ni) {
            float v = acc[mi][ni][r] + bv2[ni];
            v = v > 0.f ? v : 0.f;
            hrow[ni * 16 + lc] = f2bf(v);
          }
        }
      }
    }
  } else {
    const int totT = seg[NEXP];
#pragma unroll
    for (int mi = 0; mi < 4; ++mi) {
#pragma unroll
      for (int r = 0; r < 4; ++r) {
        int row = m0 + wr * 64 + mi * 16 + lr + r;
        if (row < cnt) {
          float* prow = Pt + ((size_t)ks * totT + s0 + row) * ND + n0 + wc * 64;
#pragma unroll
          for (int ni = 0; ni < 4; ++ni)
            prow[ni * 16 + lc] = acc[mi][ni][r];
        }
      }
    }
  }
}

// Fused: GEMM1 blocks first, then persistent W2-transpose blocks.
// W2t is only read by the NEXT launch (gemm2) -> completion guaranteed.
__global__ __launch_bounds__(256, 4) void gemm1_fused_k(
    const u16* __restrict__ Xg, const u16* __restrict__ W1t,
    const float* __restrict__ b1, const int* __restrict__ seg,
    const int* __restrict__ ntile, const int* __restrict__ tile_e,
    const int* __restrict__ tile_m, u16* __restrict__ H1,
    const float* __restrict__ W2, u16* __restrict__ W2t, int ng1) {
  __shared__ __align__(16) u16 sh[2 * BM * BK];   // 32KB; convt uses 17408B
  const int bid = blockIdx.x;
  if (bid < ng1) {
    gemm_body<HD, DFF, 0, 1>(sh, sh + BM * BK, Xg, W1t, b1, seg, ntile, tile_e,
                             tile_m, H1, nullptr, bid % (DFF / BN), bid / (DFF / BN), 0);
  } else {
    convt_quad<DFF, HD>(W2, W2t, (bid - ng1) * 4, sh);   // W2 [E][DFF][HD] -> [E][HD][DFF]
  }
}

__global__ __launch_bounds__(256, 4) void gemm2_k(
    const u16* __restrict__ H1, const u16* __restrict__ W2t,
    const int* __restrict__ seg, const int* __restrict__ ntile,
    const int* __restrict__ tile_e, const int* __restrict__ tile_m,
    float* __restrict__ Pt) {
  __shared__ __align__(16) u16 sh[2 * BM * BK];
  gemm_body<DFF, HD, 2, 4>(sh, sh + BM * BK, H1, W2t, nullptr, seg, ntile, tile_e,
                           tile_m, nullptr, Pt, blockIdx.x, blockIdx.y, blockIdx.z);
}

// out[perm[pos]] = gate[pos] * (b2[e] + sum_ks Pt[ks][pos][:])
__global__ __launch_bounds__(256) void reduce_k(const float* __restrict__ Pt,
    const float* __restrict__ b2, const int* __restrict__ perm,
    const float* __restrict__ gatep, const int* __restrict__ tok_exp,
    float* __restrict__ out) {
  const int pos = blockIdx.x;
  const int totT = gridDim.x;
  const int tok = perm[pos];
  const float g = gatep[pos];
  const int e = tok_exp[tok];
  const int h = threadIdx.x * 4;
  float4 s = *(const float4*)(Pt + ((size_t)0 * totT + pos) * HD + h);
#pragma unroll
  for (int k = 1; k < 4; ++k) {
    float4 p = *(const float4*)(Pt + ((size_t)k * totT + pos) * HD + h);
    s.x += p.x; s.y += p.y; s.z += p.z; s.w += p.w;
  }
  float4 b = *(const float4*)(b2 + (size_t)e * HD + h);
  float4 o;
  o.x = (s.x + b.x) * g; o.y = (s.y + b.y) * g;
  o.z = (s.z + b.z) * g; o.w = (s.w + b.w) * g;
  *(float4*)(out + (size_t)tok * HD + h) = o;
}

extern "C" void kernel_launch(void* const* d_in, const int* in_sizes, int n_in,
                              void* d_out, int out_size, void* d_ws, size_t ws_size,
                              hipStream_t stream) {
  const float* x  = (const float*)d_in[0];
  const float* Wr = (const float*)d_in[1];
  const float* br = (const float*)d_in[2];
  const float* W1 = (const float*)d_in[3];
  const float* b1 = (const float*)d_in[4];
  const float* W2 = (const float*)d_in[5];
  const float* b2 = (const float*)d_in[6];
  float* out = (float*)d_out;

  const int T = in_sizes[0] / HD;   // 4096 tokens
  char* ws = (char*)d_ws;
  int*   counts   = (int*)(ws + 0);
  int*   cursor   = (int*)(ws + 64);
  int*   seg      = (int*)(ws + 128);
  int*   ntile    = (int*)(ws + 192);
  int*   tile_e   = (int*)(ws + 256);
  int*   tile_m   = (int*)(ws + 512);
  int*   tok_exp  = (int*)(ws + 1024);
  float* tok_gate = (float*)(ws + 1024 + 4 * (size_t)T);
  int*   perm     = (int*)(ws + 1024 + 8 * (size_t)T);
  float* gatep    = (float*)(ws + 1024 + 12 * (size_t)T);
  u16*   Xg       = (u16*)(ws + 1024 + 16 * (size_t)T);                       // T*HD bf16 (8MB)
  u16*   H1       = (u16*)(ws + 1024 + 16 * (size_t)T + 2 * (size_t)T * HD);  // T*DFF bf16 (32MB)
  size_t off2     = 1024 + 16 * (size_t)T + 2 * (size_t)T * HD + 2 * (size_t)T * DFF;
  u16*   W1t      = (u16*)(ws + off2);                                        // E*DFF*HD bf16 (64MB)
  u16*   W2t      = (u16*)(ws + off2 + 2 * (size_t)NEXP * HD * DFF);          // E*HD*DFF bf16 (64MB)
  float* Pt       = (float*)W1t;   // GEMM2 split-K partials (4*T*HD f32 = 64MB) reuse W1t
  u16*   Xbf      = H1;            // bf16 x (8MB) lives in H1's region until gather is done

  hipLaunchKernelGGL(zero_k, dim3(1), dim3(64), 0, stream, counts);
  const int NCB = NEXP * (HD / 128) * (DFF / 64) / 4;   // 1024 convt blocks (4 tiles each)
  hipLaunchKernelGGL(prep1_k, dim3(NCB + T / 4), dim3(256), 0, stream,
                     x, Wr, br, counts, tok_exp, tok_gate, W1, W1t, Xbf, T);
  hipLaunchKernelGGL(scan_k, dim3(1), dim3(64), 0, stream, counts, seg, cursor, ntile, tile_e, tile_m);
  hipLaunchKernelGGL(gather_k, dim3(T / 4), dim3(256), 0, stream,
                     Xbf, tok_exp, tok_gate, cursor, perm, gatep, Xg);
  const int maxtile = (T + BM - 1) / BM + NEXP - 1;   // 39 worst case
  const int ng1 = (DFF / BN) * maxtile;               // 1248 GEMM1 blocks
  hipLaunchKernelGGL(gemm1_fused_k, dim3(ng1 + NCB), dim3(256), 0, stream,
                     Xg, W1t, b1, seg, ntile, tile_e, tile_m, H1, W2, W2t, ng1);
  hipLaunchKernelGGL(gemm2_k, dim3(HD / BN, maxtile, 4), dim3(256), 0, stream,
                     H1, W2t, seg, ntile, tile_e, tile_m, Pt);
  hipLaunchKernelGGL(reduce_k, dim3(T), dim3(256), 0, stream, Pt, b2, perm, gatep, tok_exp, out);
}